// Round 2
// baseline (3557.690 us; speedup 1.0000x reference)
//
#include <hip/hip_runtime.h>
#include <stdint.h>

#define NP 2048
#define KNN 40
#define CAP 160          // candidate buffer per row
#define MARGIN 16384u    // fp32-ulp slack covering fp32-pipeline error * exponent ratio

__device__ __forceinline__ unsigned fOrd(float f) {
    unsigned u = __float_as_uint(f);
    return u ^ ((unsigned)((int)u >> 31) | 0x80000000u);
}
__device__ __forceinline__ unsigned long long dOrd(double d) {
    unsigned long long u = (unsigned long long)__double_as_longlong(d);
    return u ^ (((unsigned long long)((long long)u >> 63)) | 0x8000000000000000ull);
}

// ---------------------------------------------------------------------------
// prep: per point compute xx = sum x^2, p[o] = Wd[o,:]·x, r[o] = (Wc-Wd)[o,:]·x
// layouts: p,r [B][N][32]; xx [B][N]
// ---------------------------------------------------------------------------
template<int C>
__global__ void prep_kernel(const float* __restrict__ X, long bstride,
                            const float* __restrict__ W,
                            float* __restrict__ p, float* __restrict__ r,
                            float* __restrict__ xx) {
    __shared__ float wdT[C][32];
    __shared__ float wrT[C][32];
    int tid = threadIdx.x;
    for (int i = tid; i < 32 * C; i += 256) {
        int o = i / C, c = i - o * C;
        float wd = W[o * 2 * C + c];
        float wc = W[o * 2 * C + C + c];
        wdT[c][o] = wd;
        wrT[c][o] = wc - wd;
    }
    __syncthreads();
    int lane = tid & 63;
    int o = lane & 31;
    int h = lane >> 5;
    int wv = tid >> 6;
    int flat = blockIdx.x * 8 + wv * 2 + h;   // 2048 wgs * 8 points = B*N
    int b = flat >> 11, n = flat & 2047;
    const float* Xb = X + (long)b * bstride + n;
    float pacc = 0.f, racc = 0.f, xxa = 0.f;
#pragma unroll
    for (int c = 0; c < C; c++) {
        float xv = Xb[(long)c * NP];
        pacc = fmaf(wdT[c][o], xv, pacc);
        racc = fmaf(wrT[c][o], xv, racc);
        xxa += xv * xv;
    }
    long base = ((long)b * NP + n) * 32 + o;
    p[base] = pacc;
    r[base] = racc;
    if (o == 0) xx[b * NP + n] = xxa;
}

// ---------------------------------------------------------------------------
// knn: per (b,n) row:
//  pass 1: fp32 tiled distances -> fp32 rank-40 key via ballot bisection
//  pass 2: candidates {key <= t40 + MARGIN ulps} (ascending m), refined in
//          float64 (matches np float64 ordering), 64-bit bisect -> exact
//          top-40 with lowest-index tie-break; fused gather-reduce of p.
// wg = 256 = 4 waves; each wave owns 2 rows; dist row in regs (32/lane).
// ---------------------------------------------------------------------------
template<int C, int NQ>
__global__ void knn_kernel(const float* __restrict__ X, long bstride,
                           const float* __restrict__ p, const float* __restrict__ r,
                           const float* __restrict__ xx,
                           float* __restrict__ mmax, float* __restrict__ mmin,
                           float* __restrict__ sums) {
    constexpr int CP = NQ * 4;
    constexpr int S = (CP % 8 == 0) ? CP + 4 : CP + 8;   // row stride, S%8==4 -> spread banks
    __shared__ __align__(16) float xt[128][S];
    __shared__ float xxt[128];
    __shared__ int sel[8][KNN];
    __shared__ int cand[8][CAP];
    __shared__ float S1loc[32], S2loc[32];
    int tid = threadIdx.x;
    if (tid < 32) { S1loc[tid] = 0.f; S2loc[tid] = 0.f; }
    int lane = tid & 63;
    int wv = tid >> 6;
    int b = blockIdx.x >> 8;              // 256 wgs per batch
    int n0 = (blockIdx.x & 255) * 8;
    int nA = n0 + wv * 2, nB = nA + 1;
    const float* Xb = X + (long)b * bstride;

    float4 xnA[NQ], xnB[NQ];
#pragma unroll
    for (int q = 0; q < NQ; q++) {
        float va[4], vb[4];
#pragma unroll
        for (int j = 0; j < 4; j++) {
            int c = q * 4 + j;
            va[j] = (c < C) ? Xb[(long)c * NP + nA] : 0.f;
            vb[j] = (c < C) ? Xb[(long)c * NP + nB] : 0.f;
        }
        xnA[q] = make_float4(va[0], va[1], va[2], va[3]);
        xnB[q] = make_float4(vb[0], vb[1], vb[2], vb[3]);
    }
    float xxnA = xx[b * NP + nA];
    float xxnB = xx[b * NP + nB];

    unsigned uA[32], uB[32];
    for (int t = 0; t < 16; t++) {
        __syncthreads();
        for (int i = tid; i < C * 128; i += 256) {
            int c = i >> 7, m = i & 127;
            xt[m][c] = Xb[(long)c * NP + t * 128 + m];
        }
        if (CP > C) {
            for (int i = tid; i < (CP - C) * 128; i += 256) {
                int c = C + (i >> 7), m = i & 127;
                xt[m][c] = 0.f;
            }
        }
        if (tid < 128) xxt[tid] = xx[b * NP + t * 128 + tid];
        __syncthreads();
#pragma unroll
        for (int jh = 0; jh < 2; jh++) {
            int m = jh * 64 + lane;
            float ia = 0.f, ib = 0.f;
#pragma unroll
            for (int q = 0; q < NQ; q++) {
                float4 xv = *(const float4*)&xt[m][q * 4];
                ia = fmaf(xnA[q].x, xv.x, ia);
                ia = fmaf(xnA[q].y, xv.y, ia);
                ia = fmaf(xnA[q].z, xv.z, ia);
                ia = fmaf(xnA[q].w, xv.w, ia);
                ib = fmaf(xnB[q].x, xv.x, ib);
                ib = fmaf(xnB[q].y, xv.y, ib);
                ib = fmaf(xnB[q].z, xv.z, ib);
                ib = fmaf(xnB[q].w, xv.w, ib);
            }
            float xxm = xxt[m];
            float dA = (xxnA - 2.0f * ia) + xxm;
            float dB = (xxnB - 2.0f * ib) + xxm;
            uA[t * 2 + jh] = fOrd(dA);
            uB[t * 2 + jh] = fOrd(dB);
        }
    }

    unsigned long long lmlt = (1ull << lane) - 1ull;
    auto do_row = [&](unsigned (&u)[32], const float4* xn, int row, int n) {
        // --- pass 1 select: fp32 rank-40 key ---
        unsigned lo = 0u, hi = 0xFFFFFFFFu;
        while (lo < hi) {
            unsigned mid = lo + ((hi - lo) >> 1);
            int cnt = 0;
#pragma unroll
            for (int j = 0; j < 32; j++)
                cnt += __popcll(__ballot(u[j] <= mid));
            if (cnt >= KNN) hi = mid; else lo = mid + 1;
        }
        unsigned thr = (lo > 0xFFFFFFFFu - MARGIN) ? 0xFFFFFFFFu : lo + MARGIN;
        // --- candidate list, ascending m ---
        int base = 0;
#pragma unroll
        for (int j = 0; j < 32; j++) {
            bool pr = (u[j] <= thr);
            unsigned long long mk = __ballot(pr);
            if (pr) {
                int pos = base + __popcll(mk & lmlt);
                if (pos < CAP) cand[row][pos] = j * 64 + lane;
            }
            base += __popcll(mk);
        }
        int cnt = base < CAP ? base : CAP;
        // --- refine candidates in float64 (matches np float64 ordering) ---
        double xxdn = 0.0;
#pragma unroll
        for (int q = 0; q < NQ; q++) {
            xxdn += (double)xn[q].x * (double)xn[q].x;
            xxdn += (double)xn[q].y * (double)xn[q].y;
            xxdn += (double)xn[q].z * (double)xn[q].z;
            xxdn += (double)xn[q].w * (double)xn[q].w;
        }
        unsigned long long key[3]; int midx[3];
#pragma unroll
        for (int s3 = 0; s3 < 3; s3++) {
            int slot = s3 * 64 + lane;
            key[s3] = ~0ull; midx[s3] = 0;
            if (slot < cnt) {
                int m = cand[row][slot];
                midx[s3] = m;
                double inner = 0.0, xxm = 0.0;
#pragma unroll
                for (int q = 0; q < NQ; q++) {
#pragma unroll
                    for (int jj = 0; jj < 4; jj++) {
                        int c = q * 4 + jj;
                        if (c < C) {
                            float xmv = Xb[(long)c * NP + m];
                            float xqv = (jj == 0) ? xn[q].x : (jj == 1) ? xn[q].y
                                       : (jj == 2) ? xn[q].z : xn[q].w;
                            inner += (double)xqv * (double)xmv;
                            xxm   += (double)xmv * (double)xmv;
                        }
                    }
                }
                double dd = (xxdn - 2.0 * inner) + xxm;
                key[s3] = dOrd(dd);
            }
        }
        // --- 64-bit bisect for rank-40 among candidates ---
        unsigned long long lo64 = 0ull, hi64 = ~0ull;
        while (lo64 < hi64) {
            unsigned long long mid = lo64 + ((hi64 - lo64) >> 1);
            int c2 = 0;
#pragma unroll
            for (int s3 = 0; s3 < 3; s3++)
                c2 += __popcll(__ballot(key[s3] <= mid));
            if (c2 >= KNN) hi64 = mid; else lo64 = mid + 1;
        }
        // --- emit top-40, slot order (= ascending m) breaks ties ---
        int b2 = 0;
#pragma unroll
        for (int s3 = 0; s3 < 3; s3++) {
            bool pr = (key[s3] < lo64);
            unsigned long long mk = __ballot(pr);
            if (pr) sel[row][b2 + __popcll(mk & lmlt)] = midx[s3];
            b2 += __popcll(mk);
        }
#pragma unroll
        for (int s3 = 0; s3 < 3; s3++) {
            bool pr = (key[s3] == lo64);
            unsigned long long mk = __ballot(pr);
            if (pr) {
                int pos = b2 + __popcll(mk & lmlt);
                if (pos < KNN) sel[row][pos] = midx[s3];
            }
            b2 += __popcll(mk);
        }
        // --- fused gather-reduce over the selected 40: lane = (o, half) ---
        int o = lane & 31, h = lane >> 5;
        float s1 = 0.f, s2 = 0.f;
        float mx = -__builtin_inff(), mn = __builtin_inff();
        const float* pb = p + (long)b * NP * 32 + o;
        for (int k = h * 20; k < h * 20 + 20; k++) {
            int m = sel[row][k];
            float pv = pb[(long)m * 32];
            s1 += pv;
            s2 = fmaf(pv, pv, s2);
            mx = fmaxf(mx, pv);
            mn = fminf(mn, pv);
        }
        s1 += __shfl_xor(s1, 32);
        s2 += __shfl_xor(s2, 32);
        mx = fmaxf(mx, __shfl_xor(mx, 32));
        mn = fminf(mn, __shfl_xor(mn, 32));
        if (h == 0) {
            long bse = ((long)b * NP + n) * 32 + o;
            float q = r[bse];
            mmax[bse] = mx + q;
            mmin[bse] = mn + q;
            atomicAdd(&S1loc[o], s1 + 40.f * q);
            atomicAdd(&S2loc[o], fmaf(2.f * q, s1, fmaf(40.f * q, q, s2)));
        }
    };
    do_row(uA, xnA, wv * 2, nA);
    do_row(uB, xnB, wv * 2 + 1, nB);
    __syncthreads();
    if (tid < 32) {
        atomicAdd(&sums[tid], S1loc[tid]);
        atomicAdd(&sums[32 + tid], S2loc[tid]);
    }
}

// ---------------------------------------------------------------------------
// finish: per-channel BN affine from global sums, monotone max/min trick,
// LeakyReLU, residual, write slice of cat into d_out [B][128][N]
// ---------------------------------------------------------------------------
__global__ void finish_kernel(const float* __restrict__ mmax, const float* __restrict__ mmin,
                              const float* __restrict__ sums,
                              const float* __restrict__ g, const float* __restrict__ be,
                              const float* __restrict__ resid,
                              float* __restrict__ outb) {
    int id = blockIdx.x * 256 + threadIdx.x;     // B*32*N = 524288
    int b = id >> 16;
    int o = (id >> 11) & 31;
    int n = id & 2047;
    const float cntf = 655360.0f;                 // B*N*K
    float mean = sums[o] / cntf;
    float var = sums[32 + o] / cntf - mean * mean;
    float sc = g[o] / sqrtf(var + 1e-5f);
    float sh = be[o] - mean * sc;
    long bse = ((long)b * NP + n) * 32 + o;
    float v = (sc >= 0.f) ? mmax[bse] : mmin[bse];
    float y = sc * v + sh;
    y = (y >= 0.f) ? y : 0.2f * y;
    long ob = ((long)b * 128 + o) * NP + n;
    if (resid) y += resid[ob];
    outb[ob] = y;
}

// ---------------------------------------------------------------------------
// final in-place GEMM on d_out: out[b,o,n] = sum_c W5[o,c]*cat[b,c,n]
// ---------------------------------------------------------------------------
__global__ void final_gemm(const float* __restrict__ W5, float* __restrict__ out) {
    __shared__ __align__(16) float catL[128][32];
    int b = blockIdx.x >> 6;
    int n0 = (blockIdx.x & 63) * 32;
    int tid = threadIdx.x;
    for (int i = tid; i < 128 * 32; i += 256) {
        int c = i >> 5, nn = i & 31;
        catL[c][nn] = out[((long)b * 128 + c) * NP + n0 + nn];
    }
    __syncthreads();
    int og = tid >> 3, ng = tid & 7;
    int o0 = og * 4, nl = ng * 4;
    float acc[4][4] = {};
    for (int c = 0; c < 128; c++) {
        float4 cv = *(const float4*)&catL[c][nl];
#pragma unroll
        for (int i = 0; i < 4; i++) {
            float w = W5[(o0 + i) * 128 + c];
            acc[i][0] = fmaf(w, cv.x, acc[i][0]);
            acc[i][1] = fmaf(w, cv.y, acc[i][1]);
            acc[i][2] = fmaf(w, cv.z, acc[i][2]);
            acc[i][3] = fmaf(w, cv.w, acc[i][3]);
        }
    }
#pragma unroll
    for (int i = 0; i < 4; i++) {
        float4 vv = make_float4(acc[i][0], acc[i][1], acc[i][2], acc[i][3]);
        *(float4*)&out[((long)b * 128 + o0 + i) * NP + n0 + nl] = vv;
    }
}

extern "C" void kernel_launch(void* const* d_in, const int* in_sizes, int n_in,
                              void* d_out, int out_size, void* d_ws, size_t ws_size,
                              hipStream_t stream) {
    const float* x  = (const float*)d_in[0];
    const float* W1 = (const float*)d_in[1];
    const float* W2 = (const float*)d_in[2];
    const float* W3 = (const float*)d_in[3];
    const float* W4 = (const float*)d_in[4];
    const float* W5 = (const float*)d_in[5];
    const float* g1 = (const float*)d_in[6];
    const float* b1 = (const float*)d_in[7];
    const float* g2 = (const float*)d_in[8];
    const float* b2 = (const float*)d_in[9];
    const float* g3 = (const float*)d_in[10];
    const float* b3 = (const float*)d_in[11];
    const float* g4 = (const float*)d_in[12];
    const float* b4 = (const float*)d_in[13];
    float* out = (float*)d_out;
    float* ws  = (float*)d_ws;
    float* p    = ws;
    float* r    = ws + 524288;
    float* mmax = ws + 1048576;
    float* mmin = ws + 1572864;
    float* xx   = ws + 2097152;
    float* sums = ws + 2113536;
    hipMemsetAsync(sums, 0, 256 * sizeof(float), stream);

    // block 1 (C=9)
    prep_kernel<9><<<2048, 256, 0, stream>>>(x, 9L * NP, W1, p, r, xx);
    knn_kernel<9, 3><<<2048, 256, 0, stream>>>(x, 9L * NP, p, r, xx, mmax, mmin, sums);
    finish_kernel<<<2048, 256, 0, stream>>>(mmax, mmin, sums, g1, b1, nullptr, out);
    // block 2
    const float* x1 = out;
    prep_kernel<32><<<2048, 256, 0, stream>>>(x1, 128L * NP, W2, p, r, xx);
    knn_kernel<32, 8><<<2048, 256, 0, stream>>>(x1, 128L * NP, p, r, xx, mmax, mmin, sums + 64);
    finish_kernel<<<2048, 256, 0, stream>>>(mmax, mmin, sums + 64, g2, b2, x1, out + 32 * NP);
    // block 3
    const float* x2 = out + 32 * NP;
    prep_kernel<32><<<2048, 256, 0, stream>>>(x2, 128L * NP, W3, p, r, xx);
    knn_kernel<32, 8><<<2048, 256, 0, stream>>>(x2, 128L * NP, p, r, xx, mmax, mmin, sums + 128);
    finish_kernel<<<2048, 256, 0, stream>>>(mmax, mmin, sums + 128, g3, b3, x2, out + 64 * NP);
    // block 4
    const float* x3 = out + 64 * NP;
    prep_kernel<32><<<2048, 256, 0, stream>>>(x3, 128L * NP, W4, p, r, xx);
    knn_kernel<32, 8><<<2048, 256, 0, stream>>>(x3, 128L * NP, p, r, xx, mmax, mmin, sums + 192);
    finish_kernel<<<2048, 256, 0, stream>>>(mmax, mmin, sums + 192, g4, b4, x3, out + 96 * NP);

    final_gemm<<<512, 256, 0, stream>>>(W5, out);
}

// Round 3
// 1267.202 us; speedup vs baseline: 2.8075x; 2.8075x over previous
//
#include <hip/hip_runtime.h>
#include <stdint.h>

#define NP 2048
#define KNN 40
#define CAP 160          // candidate buffer per row
#define MARGIN 16384u    // fp32-ulp slack covering fp32-pipeline error * exponent ratio

__device__ __forceinline__ unsigned fOrd(float f) {
    unsigned u = __float_as_uint(f);
    return u ^ ((unsigned)((int)u >> 31) | 0x80000000u);
}
__device__ __forceinline__ unsigned long long dOrd(double d) {
    unsigned long long u = (unsigned long long)__double_as_longlong(d);
    return u ^ (((unsigned long long)((long long)u >> 63)) | 0x8000000000000000ull);
}

// ---------------------------------------------------------------------------
// prep: per point compute xx = sum x^2, p[o] = Wd[o,:]·x, r[o] = (Wc-Wd)[o,:]·x
// layouts: p,r [B][N][32]; xx [B][N]
// ---------------------------------------------------------------------------
template<int C>
__global__ void prep_kernel(const float* __restrict__ X, long bstride,
                            const float* __restrict__ W,
                            float* __restrict__ p, float* __restrict__ r,
                            float* __restrict__ xx) {
    __shared__ float wdT[C][32];
    __shared__ float wrT[C][32];
    int tid = threadIdx.x;
    for (int i = tid; i < 32 * C; i += 256) {
        int o = i / C, c = i - o * C;
        float wd = W[o * 2 * C + c];
        float wc = W[o * 2 * C + C + c];
        wdT[c][o] = wd;
        wrT[c][o] = wc - wd;
    }
    __syncthreads();
    int lane = tid & 63;
    int o = lane & 31;
    int h = lane >> 5;
    int wv = tid >> 6;
    int flat = blockIdx.x * 8 + wv * 2 + h;   // 2048 wgs * 8 points = B*N
    int b = flat >> 11, n = flat & 2047;
    const float* Xb = X + (long)b * bstride + n;
    float pacc = 0.f, racc = 0.f, xxa = 0.f;
#pragma unroll
    for (int c = 0; c < C; c++) {
        float xv = Xb[(long)c * NP];
        pacc = fmaf(wdT[c][o], xv, pacc);
        racc = fmaf(wrT[c][o], xv, racc);
        xxa += xv * xv;
    }
    long base = ((long)b * NP + n) * 32 + o;
    p[base] = pacc;
    r[base] = racc;
    if (o == 0) xx[b * NP + n] = xxa;
}

// ---------------------------------------------------------------------------
// knn: per (b,n) row:
//  pass 1: fp32 tiled distances (tile in LDS [c][m], conflict-free scalar
//          reads) -> top-20-bit rank-40 key via ballot bisection
//  pass 2: candidates {key <= thr} (ascending m), refined in float64
//          (matches np float64 ordering), 64-bit bisect -> exact top-40
//          with lowest-index tie-break; fused gather-reduce of p.
// wg = 256 = 4 waves; each wave owns 2 rows; dist row in regs (32/lane).
// __launch_bounds__(256,2): allow 256 VGPR so the 64 key regs DON'T spill.
// ---------------------------------------------------------------------------
template<int C>
__global__ __launch_bounds__(256, 2)
void knn_kernel(const float* __restrict__ X, long bstride,
                const float* __restrict__ p, const float* __restrict__ r,
                const float* __restrict__ xx,
                float* __restrict__ mmax, float* __restrict__ mmin,
                float* __restrict__ sums) {
    __shared__ __align__(16) float xt[C * 128];   // [c][m] tile, m contiguous
    __shared__ float xxt[128];
    __shared__ int sel[8][KNN];
    __shared__ int cand[8][CAP];
    __shared__ float S1loc[32], S2loc[32];
    int tid = threadIdx.x;
    if (tid < 32) { S1loc[tid] = 0.f; S2loc[tid] = 0.f; }
    int lane = tid & 63;
    int wv = tid >> 6;
    int b = blockIdx.x >> 8;              // 256 wgs per batch
    int n0 = (blockIdx.x & 255) * 8;
    int nA = n0 + wv * 2, nB = nA + 1;
    const float* Xb = X + (long)b * bstride;

    // wave-uniform query vectors
    float xqA[C], xqB[C];
#pragma unroll
    for (int c = 0; c < C; c++) {
        xqA[c] = Xb[(long)c * NP + nA];
        xqB[c] = Xb[(long)c * NP + nB];
    }
    float xxnA = xx[b * NP + nA];
    float xxnB = xx[b * NP + nB];

    unsigned uA[32], uB[32];
    for (int t = 0; t < 16; t++) {
        __syncthreads();
        // stage tile: float4 global load -> b128 LDS write, stride-1
        for (int i = tid; i < C * 32; i += 256) {
            int c = i >> 5, g = i & 31;
            float4 v = *(const float4*)&Xb[(long)c * NP + t * 128 + g * 4];
            *(float4*)&xt[c * 128 + g * 4] = v;
        }
        if (tid < 128) xxt[tid] = xx[b * NP + t * 128 + tid];
        __syncthreads();
#pragma unroll
        for (int jh = 0; jh < 2; jh++) {
            int m = jh * 64 + lane;
            float ia = 0.f, ib = 0.f;
#pragma unroll
            for (int c = 0; c < C; c++) {
                float xv = xt[c * 128 + m];     // bank = lane%32: conflict-free
                ia = fmaf(xqA[c], xv, ia);
                ib = fmaf(xqB[c], xv, ib);
            }
            float xxm = xxt[m];
            float dA = (xxnA - 2.0f * ia) + xxm;   // ref formula/rounding
            float dB = (xxnB - 2.0f * ib) + xxm;
            uA[t * 2 + jh] = fOrd(dA);
            uB[t * 2 + jh] = fOrd(dB);
        }
    }

    unsigned long long lmlt = (1ull << lane) - 1ull;
    auto do_row = [&](unsigned (&u)[32], const float* xq, int row, int n) {
        // --- pass 1 select: rank-40 on top-20 bits of fp32 key ---
        unsigned lo = 0u, hi = (1u << 20) - 1u;
        while (lo < hi) {
            unsigned mid = (lo + hi) >> 1;
            int cnt = 0;
#pragma unroll
            for (int j = 0; j < 32; j++)
                cnt += __popcll(__ballot((u[j] >> 12) <= mid));
            if (cnt >= KNN) hi = mid; else lo = mid + 1;
        }
        unsigned thr = (lo << 12) | 0xFFFu;
        thr = (thr > 0xFFFFFFFFu - MARGIN) ? 0xFFFFFFFFu : thr + MARGIN;
        // --- candidate list, ascending m ---
        int base = 0;
#pragma unroll
        for (int j = 0; j < 32; j++) {
            bool pr = (u[j] <= thr);
            unsigned long long mk = __ballot(pr);
            if (pr) {
                int pos = base + __popcll(mk & lmlt);
                if (pos < CAP) cand[row][pos] = j * 64 + lane;
            }
            base += __popcll(mk);
        }
        int cnt = base < CAP ? base : CAP;
        // --- refine candidates in float64 (matches np float64 ordering) ---
        double xxdn = 0.0;
#pragma unroll
        for (int c = 0; c < C; c++)
            xxdn += (double)xq[c] * (double)xq[c];
        unsigned long long key[3]; int midx[3];
#pragma unroll
        for (int s3 = 0; s3 < 3; s3++) {
            int slot = s3 * 64 + lane;
            key[s3] = ~0ull; midx[s3] = 0;
            if (slot < cnt) {
                int m = cand[row][slot];
                midx[s3] = m;
                double inner = 0.0, xxm = 0.0;
#pragma unroll
                for (int c = 0; c < C; c++) {
                    float xmv = Xb[(long)c * NP + m];
                    inner += (double)xq[c] * (double)xmv;
                    xxm   += (double)xmv * (double)xmv;
                }
                double dd = (xxdn - 2.0 * inner) + xxm;
                key[s3] = dOrd(dd);
            }
        }
        // --- 64-bit bisect for rank-40 among candidates ---
        unsigned long long lo64 = 0ull, hi64 = ~0ull;
        while (lo64 < hi64) {
            unsigned long long mid = lo64 + ((hi64 - lo64) >> 1);
            int c2 = 0;
#pragma unroll
            for (int s3 = 0; s3 < 3; s3++)
                c2 += __popcll(__ballot(key[s3] <= mid));
            if (c2 >= KNN) hi64 = mid; else lo64 = mid + 1;
        }
        // --- emit top-40, slot order (= ascending m) breaks ties ---
        int b2 = 0;
#pragma unroll
        for (int s3 = 0; s3 < 3; s3++) {
            bool pr = (key[s3] < lo64);
            unsigned long long mk = __ballot(pr);
            if (pr) sel[row][b2 + __popcll(mk & lmlt)] = midx[s3];
            b2 += __popcll(mk);
        }
#pragma unroll
        for (int s3 = 0; s3 < 3; s3++) {
            bool pr = (key[s3] == lo64);
            unsigned long long mk = __ballot(pr);
            if (pr) {
                int pos = b2 + __popcll(mk & lmlt);
                if (pos < KNN) sel[row][pos] = midx[s3];
            }
            b2 += __popcll(mk);
        }
        // --- fused gather-reduce over the selected 40: lane = (o, half) ---
        int o = lane & 31, h = lane >> 5;
        float s1 = 0.f, s2 = 0.f;
        float mx = -__builtin_inff(), mn = __builtin_inff();
        const float* pb = p + (long)b * NP * 32 + o;
        for (int k = h * 20; k < h * 20 + 20; k++) {
            int m = sel[row][k];
            float pv = pb[(long)m * 32];
            s1 += pv;
            s2 = fmaf(pv, pv, s2);
            mx = fmaxf(mx, pv);
            mn = fminf(mn, pv);
        }
        s1 += __shfl_xor(s1, 32);
        s2 += __shfl_xor(s2, 32);
        mx = fmaxf(mx, __shfl_xor(mx, 32));
        mn = fminf(mn, __shfl_xor(mn, 32));
        if (h == 0) {
            long bse = ((long)b * NP + n) * 32 + o;
            float q = r[bse];
            mmax[bse] = mx + q;
            mmin[bse] = mn + q;
            atomicAdd(&S1loc[o], s1 + 40.f * q);
            atomicAdd(&S2loc[o], fmaf(2.f * q, s1, fmaf(40.f * q, q, s2)));
        }
    };
    do_row(uA, xqA, wv * 2, nA);
    do_row(uB, xqB, wv * 2 + 1, nB);
    __syncthreads();
    if (tid < 32) {
        atomicAdd(&sums[tid], S1loc[tid]);
        atomicAdd(&sums[32 + tid], S2loc[tid]);
    }
}

// ---------------------------------------------------------------------------
// finish: per-channel BN affine from global sums, monotone max/min trick,
// LeakyReLU, residual, write slice of cat into d_out [B][128][N]
// ---------------------------------------------------------------------------
__global__ void finish_kernel(const float* __restrict__ mmax, const float* __restrict__ mmin,
                              const float* __restrict__ sums,
                              const float* __restrict__ g, const float* __restrict__ be,
                              const float* __restrict__ resid,
                              float* __restrict__ outb) {
    int id = blockIdx.x * 256 + threadIdx.x;     // B*32*N = 524288
    int b = id >> 16;
    int o = (id >> 11) & 31;
    int n = id & 2047;
    const float cntf = 655360.0f;                 // B*N*K
    float mean = sums[o] / cntf;
    float var = sums[32 + o] / cntf - mean * mean;
    float sc = g[o] / sqrtf(var + 1e-5f);
    float sh = be[o] - mean * sc;
    long bse = ((long)b * NP + n) * 32 + o;
    float v = (sc >= 0.f) ? mmax[bse] : mmin[bse];
    float y = sc * v + sh;
    y = (y >= 0.f) ? y : 0.2f * y;
    long ob = ((long)b * 128 + o) * NP + n;
    if (resid) y += resid[ob];
    outb[ob] = y;
}

// ---------------------------------------------------------------------------
// final in-place GEMM on d_out: out[b,o,n] = sum_c W5[o,c]*cat[b,c,n]
// ---------------------------------------------------------------------------
__global__ void final_gemm(const float* __restrict__ W5, float* __restrict__ out) {
    __shared__ __align__(16) float catL[128][32];
    int b = blockIdx.x >> 6;
    int n0 = (blockIdx.x & 63) * 32;
    int tid = threadIdx.x;
    for (int i = tid; i < 128 * 32; i += 256) {
        int c = i >> 5, nn = i & 31;
        catL[c][nn] = out[((long)b * 128 + c) * NP + n0 + nn];
    }
    __syncthreads();
    int og = tid >> 3, ng = tid & 7;
    int o0 = og * 4, nl = ng * 4;
    float acc[4][4] = {};
    for (int c = 0; c < 128; c++) {
        float4 cv = *(const float4*)&catL[c][nl];
#pragma unroll
        for (int i = 0; i < 4; i++) {
            float w = W5[(o0 + i) * 128 + c];
            acc[i][0] = fmaf(w, cv.x, acc[i][0]);
            acc[i][1] = fmaf(w, cv.y, acc[i][1]);
            acc[i][2] = fmaf(w, cv.z, acc[i][2]);
            acc[i][3] = fmaf(w, cv.w, acc[i][3]);
        }
    }
#pragma unroll
    for (int i = 0; i < 4; i++) {
        float4 vv = make_float4(acc[i][0], acc[i][1], acc[i][2], acc[i][3]);
        *(float4*)&out[((long)b * 128 + o0 + i) * NP + n0 + nl] = vv;
    }
}

extern "C" void kernel_launch(void* const* d_in, const int* in_sizes, int n_in,
                              void* d_out, int out_size, void* d_ws, size_t ws_size,
                              hipStream_t stream) {
    const float* x  = (const float*)d_in[0];
    const float* W1 = (const float*)d_in[1];
    const float* W2 = (const float*)d_in[2];
    const float* W3 = (const float*)d_in[3];
    const float* W4 = (const float*)d_in[4];
    const float* W5 = (const float*)d_in[5];
    const float* g1 = (const float*)d_in[6];
    const float* b1 = (const float*)d_in[7];
    const float* g2 = (const float*)d_in[8];
    const float* b2 = (const float*)d_in[9];
    const float* g3 = (const float*)d_in[10];
    const float* b3 = (const float*)d_in[11];
    const float* g4 = (const float*)d_in[12];
    const float* b4 = (const float*)d_in[13];
    float* out = (float*)d_out;
    float* ws  = (float*)d_ws;
    float* p    = ws;
    float* r    = ws + 524288;
    float* mmax = ws + 1048576;
    float* mmin = ws + 1572864;
    float* xx   = ws + 2097152;
    float* sums = ws + 2113536;
    hipMemsetAsync(sums, 0, 256 * sizeof(float), stream);

    // block 1 (C=9)
    prep_kernel<9><<<2048, 256, 0, stream>>>(x, 9L * NP, W1, p, r, xx);
    knn_kernel<9><<<2048, 256, 0, stream>>>(x, 9L * NP, p, r, xx, mmax, mmin, sums);
    finish_kernel<<<2048, 256, 0, stream>>>(mmax, mmin, sums, g1, b1, nullptr, out);
    // block 2
    const float* x1 = out;
    prep_kernel<32><<<2048, 256, 0, stream>>>(x1, 128L * NP, W2, p, r, xx);
    knn_kernel<32><<<2048, 256, 0, stream>>>(x1, 128L * NP, p, r, xx, mmax, mmin, sums + 64);
    finish_kernel<<<2048, 256, 0, stream>>>(mmax, mmin, sums + 64, g2, b2, x1, out + 32 * NP);
    // block 3
    const float* x2 = out + 32 * NP;
    prep_kernel<32><<<2048, 256, 0, stream>>>(x2, 128L * NP, W3, p, r, xx);
    knn_kernel<32><<<2048, 256, 0, stream>>>(x2, 128L * NP, p, r, xx, mmax, mmin, sums + 128);
    finish_kernel<<<2048, 256, 0, stream>>>(mmax, mmin, sums + 128, g3, b3, x2, out + 64 * NP);
    // block 4
    const float* x3 = out + 64 * NP;
    prep_kernel<32><<<2048, 256, 0, stream>>>(x3, 128L * NP, W4, p, r, xx);
    knn_kernel<32><<<2048, 256, 0, stream>>>(x3, 128L * NP, p, r, xx, mmax, mmin, sums + 192);
    finish_kernel<<<2048, 256, 0, stream>>>(mmax, mmin, sums + 192, g4, b4, x3, out + 96 * NP);

    final_gemm<<<512, 256, 0, stream>>>(W5, out);
}